// Round 9
// baseline (188.415 us; speedup 1.0000x reference)
//
#include <hip/hip_runtime.h>
#include <hip/hip_bf16.h>
#include <math.h>

#define B_  8
#define C_  64
#define O_  64
#define H_  128
#define W_  128
#define HW_ (H_ * W_)

typedef __attribute__((ext_vector_type(8))) short bf16x8;
typedef __attribute__((ext_vector_type(4))) float f32x4;

__device__ __forceinline__ short f2bf(float f) {
    __hip_bfloat16 h = __float2bfloat16(f);
    return *reinterpret_cast<short*>(&h);
}
__device__ __forceinline__ float bf2f(short u) {
    unsigned int v = ((unsigned int)(unsigned short)u) << 16;
    return __uint_as_float(v);
}

// ---------------------------------------------------------------------------
// Prep 1: bf16 weights, MFMA-A layout [step][mf][l15][g][8].
//   wb2 [18][4][16][4][8]  (deform)          36864 sh
//   wz2 [18][2][16][4][8]  (offset conv)     18432 sh
//   wx2 [18][1][16][4][8]  (mask conv)        9216 sh
// ---------------------------------------------------------------------------
__global__ void prep_weights(const float* __restrict__ w_off,
                             const float* __restrict__ w_mod,
                             const float* __restrict__ w_reg,
                             short* __restrict__ wb2,
                             short* __restrict__ wz2,
                             short* __restrict__ wx2) {
    int t = blockIdx.x * blockDim.x + threadIdx.x;
    if (t < 36864) {
        int step = t / 2048, r = t % 2048;
        int mf = r / 512, r2 = r % 512;
        int l = r2 / 32, r3 = r2 % 32;
        int gg = r3 / 8, j = r3 % 8;
        int kt = step >> 1, ch = step & 1;
        int o = mf * 16 + l, c = ch * 32 + gg * 8 + j;
        wb2[t] = f2bf(w_reg[(o * 64 + c) * 9 + kt]);
    }
    if (t < 18432) {
        int step = t / 1024, r = t % 1024;
        int mf = r / 512, r2 = r % 512;
        int l = r2 / 32, r3 = r2 % 32;
        int gg = r3 / 8, j = r3 % 8;
        int kt = step >> 1, ch = step & 1;
        int m = mf * 16 + l, c = ch * 32 + gg * 8 + j;
        wz2[t] = (m < 18) ? f2bf(w_off[(m * 64 + c) * 9 + kt]) : (short)0;
    }
    if (t < 9216) {
        int step = t / 512, r = t % 512;
        int l = r / 32, r3 = r % 32;
        int gg = r3 / 8, j = r3 % 8;
        int kt = step >> 1, ch = step & 1;
        int c = ch * 32 + gg * 8 + j;
        wx2[t] = (l < 9) ? f2bf(w_mod[(l * 64 + c) * 9 + kt]) : (short)0;
    }
}

// ---------------------------------------------------------------------------
// Prep 2: NCHW fp32 -> NHWC bf16 for x and z.
// ---------------------------------------------------------------------------
__global__ __launch_bounds__(256) void to_nhwc(
    const float* __restrict__ x, const float* __restrict__ z,
    unsigned short* __restrict__ xn, unsigned short* __restrict__ zn) {
    __shared__ float t[64 * 65];
    const int bid = blockIdx.x;
    const int xseg = bid & 1;
    const int y = (bid >> 1) & 127;
    const int b = bid >> 8;

#pragma unroll
    for (int arr = 0; arr < 2; ++arr) {
        const float* src = arr ? z : x;
        unsigned short* dst = arr ? zn : xn;
#pragma unroll
        for (int i = 0; i < 16; ++i) {
            int e = threadIdx.x + i * 256;
            int c = e >> 6, px = e & 63;
            t[px * 65 + c] =
                src[((size_t)(b * 64 + c) * H_ + y) * W_ + xseg * 64 + px];
        }
        __syncthreads();
#pragma unroll
        for (int i = 0; i < 2; ++i) {
            int j = threadIdx.x + i * 256;
            int px = j >> 3, q = j & 7;
            bf16x8 v;
#pragma unroll
            for (int jj = 0; jj < 8; ++jj)
                v[jj] = f2bf(t[px * 65 + q * 8 + jj]);
            *(bf16x8*)(dst +
                       ((size_t)((b * H_ + y) * W_ + xseg * 64 + px)) * 64 +
                       q * 8) = v;
        }
        __syncthreads();
    }
}

// bilinear tap parameters; offsets are int ELEMENT offsets into NHWC image
__device__ __forceinline__ void tap_params(
    int kt, int ho, int pxi, float dy, float dx, float m,
    float& w00, float& w01, float& w10, float& w11,
    int& a00, int& a01, int& a10, int& a11) {
    float py = dy + (float)(kt / 3 + ho - 1);
    float pxf = dx + (float)(kt % 3 + pxi - 1);
    float y0f = floorf(py), x0f = floorf(pxf);
    float wy1 = py - y0f, wy0 = 1.f - wy1;
    float wx1 = pxf - x0f, wx0w = 1.f - wx1;
    int y0 = (int)y0f, x0i = (int)x0f;
    int y1 = y0 + 1, x1 = x0i + 1;
    bool vy0 = (y0 >= 0) && (y0 < H_), vy1 = (y1 >= 0) && (y1 < H_);
    bool vx0 = (x0i >= 0) && (x0i < W_), vx1 = (x1 >= 0) && (x1 < W_);
    w00 = wy0 * wx0w * ((vy0 && vx0) ? m : 0.f);
    w01 = wy0 * wx1 * ((vy0 && vx1) ? m : 0.f);
    w10 = wy1 * wx0w * ((vy1 && vx0) ? m : 0.f);
    w11 = wy1 * wx1 * ((vy1 && vx1) ? m : 0.f);
    int y0c = min(max(y0, 0), H_ - 1), y1c = min(max(y1, 0), H_ - 1);
    int x0c = min(max(x0i, 0), W_ - 1), x1c = min(max(x1, 0), W_ - 1);
    a00 = (y0c * W_ + x0c) * 64;
    a01 = (y0c * W_ + x1c) * 64;
    a10 = (y1c * W_ + x0c) * 64;
    a11 = (y1c * W_ + x1c) * 64;
}

// ---------------------------------------------------------------------------
// FUSED conv + deform, one wave per 16 pixels, zero LDS, zero barriers.
// R9: __launch_bounds__(256, 1) lifts the VGPR budget so the allocator can
// give each batched load a DISTINCT destination register. R8's failure mode:
// at the 65-128 VGPR occupancy band the allocator reused load-dst registers,
// forcing a waitcnt between consecutive loads (m=1, ~450cy/load). With the
// budget freed, each tap's 10-16 loads stay in flight together (one L2
// latency per tap) and the binding constraint moves to TA line throughput.
// ---------------------------------------------------------------------------
__global__ __launch_bounds__(256, 1) void dcn_fused(
    const unsigned short* __restrict__ zn, const unsigned short* __restrict__ xn,
    const short* __restrict__ wb2, const short* __restrict__ wz2,
    const short* __restrict__ wx2,
    const float* __restrict__ b_off, const float* __restrict__ b_mod,
    float* __restrict__ out)
{
    const int tid = threadIdx.x;
    const int lane = tid & 63;
    const int wv = tid >> 6;
    const int l15 = lane & 15;
    const int g = lane >> 4;

    // XCD swizzle: 2048 blocks = 8 XCDs x 256; one image per XCD L2.
    int bid = (int)blockIdx.x;
    bid = (bid & 7) * 256 + (bid >> 3);

    const int p0 = (bid * 4 + wv) * 16;
    const int b = p0 / HW_;
    const int pix0 = p0 % HW_;
    const int ho = pix0 / W_;
    const int wx0 = pix0 % W_;
    const int px = wx0 + l15;

    const unsigned short* znb = zn + (size_t)b * HW_ * 64;
    const unsigned short* xnb = xn + (size_t)b * HW_ * 64;
    const int g8 = g * 8;

    // ---------------- Phase A: offset/mask convs ----------------
    f32x4 A0 = {0.f, 0.f, 0.f, 0.f}, A1 = A0, A2 = A0;
    const bf16x8 vzero = {0, 0, 0, 0, 0, 0, 0, 0};

#pragma unroll
    for (int kt = 0; kt < 9; ++kt) {
        const int iy = ho + kt / 3 - 1;
        const int ix = px + kt % 3 - 1;
        const bool v = (iy >= 0) && (iy < H_) && (ix >= 0) && (ix < W_);
        // branchless: clamped address, select-zero after load
        const int iyc = min(max(iy, 0), H_ - 1);
        const int ixc = min(max(ix, 0), W_ - 1);
        const int base = (iyc * W_ + ixc) * 64;
        const int s0 = kt * 2, s1 = kt * 2 + 1;

        // batch: 4 data loads + 6 weight-frag loads, all unconditional
        bf16x8 bz0 = *(const bf16x8*)(znb + base + g8);
        bf16x8 bz1 = *(const bf16x8*)(znb + base + 32 + g8);
        bf16x8 bx0 = *(const bf16x8*)(xnb + base + g8);
        bf16x8 bx1 = *(const bf16x8*)(xnb + base + 32 + g8);
        bf16x8 az00 = *(const bf16x8*)(
            wz2 + (size_t)((s0 * 2 + 0) * 16 + l15) * 32 + g8);
        bf16x8 az01 = *(const bf16x8*)(
            wz2 + (size_t)((s0 * 2 + 1) * 16 + l15) * 32 + g8);
        bf16x8 ax0 = *(const bf16x8*)(
            wx2 + (size_t)(s0 * 16 + l15) * 32 + g8);
        bf16x8 az10 = *(const bf16x8*)(
            wz2 + (size_t)((s1 * 2 + 0) * 16 + l15) * 32 + g8);
        bf16x8 az11 = *(const bf16x8*)(
            wz2 + (size_t)((s1 * 2 + 1) * 16 + l15) * 32 + g8);
        bf16x8 ax1 = *(const bf16x8*)(
            wx2 + (size_t)(s1 * 16 + l15) * 32 + g8);
        __builtin_amdgcn_sched_barrier(0);  // fence: loads above, uses below

        bz0 = v ? bz0 : vzero;
        bz1 = v ? bz1 : vzero;
        bx0 = v ? bx0 : vzero;
        bx1 = v ? bx1 : vzero;

        A0 = __builtin_amdgcn_mfma_f32_16x16x32_bf16(az00, bz0, A0, 0, 0, 0);
        A1 = __builtin_amdgcn_mfma_f32_16x16x32_bf16(az01, bz0, A1, 0, 0, 0);
        A2 = __builtin_amdgcn_mfma_f32_16x16x32_bf16(ax0, bx0, A2, 0, 0, 0);
        A0 = __builtin_amdgcn_mfma_f32_16x16x32_bf16(az10, bz1, A0, 0, 0, 0);
        A1 = __builtin_amdgcn_mfma_f32_16x16x32_bf16(az11, bz1, A1, 0, 0, 0);
        A2 = __builtin_amdgcn_mfma_f32_16x16x32_bf16(ax1, bx1, A2, 0, 0, 0);
    }

    // ---------------- Bridge: bias + sigmoid, then hoist all shfls ---------
#pragma unroll
    for (int r = 0; r < 4; ++r) A0[r] += b_off[g * 4 + r];
    if (g == 0) {
        A1[0] += b_off[16];
        A1[1] += b_off[17];
    }
    float mk[4];
#pragma unroll
    for (int r = 0; r < 4; ++r) {
        int jm = g * 4 + r;
        jm = (jm > 8) ? 8 : jm;
        mk[r] = 2.f / (1.f + expf(-(A2[r] + b_mod[jm])));
    }

    float dyA[9], dxA[9], mA[9];
#pragma unroll
    for (int kt = 0; kt < 9; ++kt) {
        if (kt < 8) {
            dyA[kt] = __shfl(A0[(2 * kt) & 3], ((2 * kt) >> 2) * 16 + l15, 64);
            dxA[kt] =
                __shfl(A0[(2 * kt + 1) & 3], ((2 * kt + 1) >> 2) * 16 + l15, 64);
        } else {
            dyA[kt] = __shfl(A1[0], l15, 64);
            dxA[kt] = __shfl(A1[1], l15, 64);
        }
        mA[kt] = __shfl(mk[kt & 3], (kt >> 2) * 16 + l15, 64);
    }

    // ---------------- Phase B: deformable conv ----------------
    f32x4 D0 = {0.f, 0.f, 0.f, 0.f}, D1 = D0, D2 = D0, D3 = D0;

#pragma unroll
    for (int kt = 0; kt < 9; ++kt) {
        float w00, w01, w10, w11;
        int a00, a01, a10, a11;
        tap_params(kt, ho, wx0 + l15, dyA[kt], dxA[kt], mA[kt], w00, w01, w10,
                   w11, a00, a01, a10, a11);
        const int s0 = kt * 2, s1 = kt * 2 + 1;

        // batch: 8 corner loads + 8 weight-frag loads, all independent
        bf16x8 c00l = *(const bf16x8*)(xnb + a00 + g8);
        bf16x8 c01l = *(const bf16x8*)(xnb + a01 + g8);
        bf16x8 c10l = *(const bf16x8*)(xnb + a10 + g8);
        bf16x8 c11l = *(const bf16x8*)(xnb + a11 + g8);
        bf16x8 c00h = *(const bf16x8*)(xnb + a00 + 32 + g8);
        bf16x8 c01h = *(const bf16x8*)(xnb + a01 + 32 + g8);
        bf16x8 c10h = *(const bf16x8*)(xnb + a10 + 32 + g8);
        bf16x8 c11h = *(const bf16x8*)(xnb + a11 + 32 + g8);
        bf16x8 a0l = *(const bf16x8*)(
            wb2 + (size_t)((s0 * 4 + 0) * 16 + l15) * 32 + g8);
        bf16x8 a1l = *(const bf16x8*)(
            wb2 + (size_t)((s0 * 4 + 1) * 16 + l15) * 32 + g8);
        bf16x8 a2l = *(const bf16x8*)(
            wb2 + (size_t)((s0 * 4 + 2) * 16 + l15) * 32 + g8);
        bf16x8 a3l = *(const bf16x8*)(
            wb2 + (size_t)((s0 * 4 + 3) * 16 + l15) * 32 + g8);
        bf16x8 a0h = *(const bf16x8*)(
            wb2 + (size_t)((s1 * 4 + 0) * 16 + l15) * 32 + g8);
        bf16x8 a1h = *(const bf16x8*)(
            wb2 + (size_t)((s1 * 4 + 1) * 16 + l15) * 32 + g8);
        bf16x8 a2h = *(const bf16x8*)(
            wb2 + (size_t)((s1 * 4 + 2) * 16 + l15) * 32 + g8);
        bf16x8 a3h = *(const bf16x8*)(
            wb2 + (size_t)((s1 * 4 + 3) * 16 + l15) * 32 + g8);
        __builtin_amdgcn_sched_barrier(0);  // fence: loads above, uses below

        bf16x8 sv0, sv1;
#pragma unroll
        for (int j = 0; j < 8; ++j) {
            float s = fmaf(bf2f(c00l[j]), w00,
                      fmaf(bf2f(c01l[j]), w01,
                      fmaf(bf2f(c10l[j]), w10, bf2f(c11l[j]) * w11)));
            sv0[j] = f2bf(s);
        }
#pragma unroll
        for (int j = 0; j < 8; ++j) {
            float s = fmaf(bf2f(c00h[j]), w00,
                      fmaf(bf2f(c01h[j]), w01,
                      fmaf(bf2f(c10h[j]), w10, bf2f(c11h[j]) * w11)));
            sv1[j] = f2bf(s);
        }
        D0 = __builtin_amdgcn_mfma_f32_16x16x32_bf16(a0l, sv0, D0, 0, 0, 0);
        D1 = __builtin_amdgcn_mfma_f32_16x16x32_bf16(a1l, sv0, D1, 0, 0, 0);
        D2 = __builtin_amdgcn_mfma_f32_16x16x32_bf16(a2l, sv0, D2, 0, 0, 0);
        D3 = __builtin_amdgcn_mfma_f32_16x16x32_bf16(a3l, sv0, D3, 0, 0, 0);
        D0 = __builtin_amdgcn_mfma_f32_16x16x32_bf16(a0h, sv1, D0, 0, 0, 0);
        D1 = __builtin_amdgcn_mfma_f32_16x16x32_bf16(a1h, sv1, D1, 0, 0, 0);
        D2 = __builtin_amdgcn_mfma_f32_16x16x32_bf16(a2h, sv1, D2, 0, 0, 0);
        D3 = __builtin_amdgcn_mfma_f32_16x16x32_bf16(a3h, sv1, D3, 0, 0, 0);
    }

    // epilogue: o = mf*16 + g*4 + r, pixel = pix0 + l15
#pragma unroll
    for (int mf = 0; mf < 4; ++mf) {
        f32x4 cc = (mf == 0) ? D0 : ((mf == 1) ? D1 : ((mf == 2) ? D2 : D3));
#pragma unroll
        for (int r = 0; r < 4; ++r) {
            const int o = mf * 16 + g * 4 + r;
            out[((size_t)b * O_ + o) * HW_ + pix0 + l15] = cc[r];
        }
    }
}

// ---------------------------------------------------------------------------
// Fallback (no workspace): fully fused fp32, slow but correct.
// ---------------------------------------------------------------------------
__global__ __launch_bounds__(256) void deform_fallback(
    const float* __restrict__ x, const float* __restrict__ z,
    const float* __restrict__ w_regp,
    const float* __restrict__ w_off, const float* __restrict__ b_off,
    const float* __restrict__ w_mod, const float* __restrict__ b_mod,
    float* __restrict__ out) {
    int p = blockIdx.x * blockDim.x + threadIdx.x;
    if (p >= B_ * HW_) return;
    int wo = p % W_;
    int ho = (p / W_) % H_;
    int b  = p / HW_;
    int pix = ho * W_ + wo;

    const float* xb = x + (size_t)b * C_ * HW_;

    float accO[18], accM[9];
#pragma unroll
    for (int j = 0; j < 18; ++j) accO[j] = b_off[j];
#pragma unroll
    for (int j = 0; j < 9; ++j) accM[j] = b_mod[j];
    const float* zb = z + (size_t)b * C_ * HW_;
#pragma unroll 1
    for (int c = 0; c < C_; ++c) {
        const float* zc = zb + c * HW_;
        const float* xc = xb + c * HW_;
#pragma unroll
        for (int ky = 0; ky < 3; ++ky) {
            int iy = ho + ky - 1;
            bool vy = (iy >= 0) && (iy < H_);
#pragma unroll
            for (int kx = 0; kx < 3; ++kx) {
                int ix = wo + kx - 1;
                bool v = vy && (ix >= 0) && (ix < W_);
                int k = ky * 3 + kx;
                float zv = v ? zc[iy * W_ + ix] : 0.f;
                float xv = v ? xc[iy * W_ + ix] : 0.f;
#pragma unroll
                for (int j = 0; j < 18; ++j)
                    accO[j] = fmaf(zv, w_off[j * 576 + c * 9 + k], accO[j]);
#pragma unroll
                for (int j = 0; j < 9; ++j)
                    accM[j] = fmaf(xv, w_mod[j * 576 + c * 9 + k], accM[j]);
            }
        }
    }
    float mv[9];
#pragma unroll
    for (int j = 0; j < 9; ++j) mv[j] = 2.f / (1.f + expf(-accM[j]));

    float acc[64];
#pragma unroll
    for (int o = 0; o < 64; ++o) acc[o] = 0.f;

#pragma unroll 1
    for (int k = 0; k < 9; ++k) {
        float dy = accO[2 * k], dx = accO[2 * k + 1], m = mv[k];
        float py = dy + (float)(k / 3 + ho - 1);
        float px = dx + (float)(k % 3 + wo - 1);
        float y0f = floorf(py), x0f = floorf(px);
        float wy1 = py - y0f, wy0 = 1.f - wy1;
        float wx1 = px - x0f, wx0 = 1.f - wx1;
        int y0 = (int)y0f, x0i = (int)x0f;
        int y1 = y0 + 1, x1 = x0i + 1;
        bool vy0 = (y0 >= 0) && (y0 < H_), vy1 = (y1 >= 0) && (y1 < H_);
        bool vx0 = (x0i >= 0) && (x0i < W_), vx1 = (x1 >= 0) && (x1 < W_);
        float w00 = wy0 * wx0 * ((vy0 && vx0) ? m : 0.f);
        float w01 = wy0 * wx1 * ((vy0 && vx1) ? m : 0.f);
        float w10 = wy1 * wx0 * ((vy1 && vx0) ? m : 0.f);
        float w11 = wy1 * wx1 * ((vy1 && vx1) ? m : 0.f);
        int y0c = min(max(y0, 0), H_ - 1), y1c = min(max(y1, 0), H_ - 1);
        int x0c = min(max(x0i, 0), W_ - 1), x1c = min(max(x1, 0), W_ - 1);
        int i00 = y0c * W_ + x0c, i01 = y0c * W_ + x1c;
        int i10 = y1c * W_ + x0c, i11 = y1c * W_ + x1c;
#pragma unroll 1
        for (int c = 0; c < C_; ++c) {
            const float* xc = xb + c * HW_;
            float val = xc[i00] * w00 + xc[i01] * w01 + xc[i10] * w10 +
                        xc[i11] * w11;
            const float* wr = w_regp + c * 9 + k;
#pragma unroll
            for (int o = 0; o < 64; ++o)
                acc[o] = fmaf(val, wr[o * 576], acc[o]);
        }
    }
    float* ob = out + (size_t)b * O_ * HW_ + pix;
#pragma unroll
    for (int o = 0; o < 64; ++o) ob[o * HW_] = acc[o];
}

// ---------------------------------------------------------------------------
extern "C" void kernel_launch(void* const* d_in, const int* in_sizes, int n_in,
                              void* d_out, int out_size, void* d_ws,
                              size_t ws_size, hipStream_t stream) {
    const float* x     = (const float*)d_in[0];
    const float* z     = (const float*)d_in[1];
    const float* w_off = (const float*)d_in[2];
    const float* b_off = (const float*)d_in[3];
    const float* w_mod = (const float*)d_in[4];
    const float* b_mod = (const float*)d_in[5];
    const float* w_reg = (const float*)d_in[6];
    float* out = (float*)d_out;

    // ws layout (bytes): wb2 73728 | wz2 36864 | wx2 18432  -> 129024
    //                    xn 16777216 | zn 16777216
    const size_t need = 129024 + 2 * 16777216ull;

    const int npix = B_ * HW_;   // 131072
    const int nblk = npix / 64;  // 2048 blocks (4 waves x 16 px)

    if (ws_size >= need) {
        short* wb2 = (short*)d_ws;
        short* wz2 = wb2 + 36864;
        short* wx2 = wz2 + 18432;
        unsigned short* xn = (unsigned short*)((char*)d_ws + 129024);
        unsigned short* zn = xn + 8388608;

        prep_weights<<<144, 256, 0, stream>>>(w_off, w_mod, w_reg, wb2, wz2,
                                              wx2);
        to_nhwc<<<2048, 256, 0, stream>>>(x, z, xn, zn);
        dcn_fused<<<nblk, 256, 0, stream>>>(zn, xn, wb2, wz2, wx2, b_off,
                                            b_mod, out);
    } else {
        deform_fallback<<<(npix + 255) / 256, 256, 0, stream>>>(
            x, z, w_reg, w_off, b_off, w_mod, b_mod, out);
    }
}

// Round 10
// 174.893 us; speedup vs baseline: 1.0773x; 1.0773x over previous
//
#include <hip/hip_runtime.h>
#include <hip/hip_bf16.h>
#include <math.h>

#define B_  8
#define C_  64
#define O_  64
#define H_  128
#define W_  128
#define HW_ (H_ * W_)

typedef __attribute__((ext_vector_type(8))) short bf16x8;
typedef __attribute__((ext_vector_type(4))) float f32x4;

__device__ __forceinline__ short f2bf(float f) {
    __hip_bfloat16 h = __float2bfloat16(f);
    return *reinterpret_cast<short*>(&h);
}
__device__ __forceinline__ float bf2f(short u) {
    unsigned int v = ((unsigned int)(unsigned short)u) << 16;
    return __uint_as_float(v);
}

// global -> LDS direct load, 16B per lane. Global addr is PER-LANE; LDS dest
// is wave-uniform base + lane*16 (HW-defined). Zero destination VGPRs.
typedef __attribute__((address_space(1))) const void cg_void;
typedef __attribute__((address_space(3))) void l_void;
__device__ __forceinline__ void gl16(const void* g, void* l) {
    __builtin_amdgcn_global_load_lds((cg_void*)g, (l_void*)l, 16, 0, 0);
}

// ---------------------------------------------------------------------------
// Prep 1: bf16 weights, MFMA-A layout [step][mf][l15][g][8].
//   wb2 [18][4][16][4][8]  (deform)          36864 sh
//   wz2 [18][2][16][4][8]  (offset conv)     18432 sh
//   wx2 [18][1][16][4][8]  (mask conv)        9216 sh
// ---------------------------------------------------------------------------
__global__ void prep_weights(const float* __restrict__ w_off,
                             const float* __restrict__ w_mod,
                             const float* __restrict__ w_reg,
                             short* __restrict__ wb2,
                             short* __restrict__ wz2,
                             short* __restrict__ wx2) {
    int t = blockIdx.x * blockDim.x + threadIdx.x;
    if (t < 36864) {
        int step = t / 2048, r = t % 2048;
        int mf = r / 512, r2 = r % 512;
        int l = r2 / 32, r3 = r2 % 32;
        int gg = r3 / 8, j = r3 % 8;
        int kt = step >> 1, ch = step & 1;
        int o = mf * 16 + l, c = ch * 32 + gg * 8 + j;
        wb2[t] = f2bf(w_reg[(o * 64 + c) * 9 + kt]);
    }
    if (t < 18432) {
        int step = t / 1024, r = t % 1024;
        int mf = r / 512, r2 = r % 512;
        int l = r2 / 32, r3 = r2 % 32;
        int gg = r3 / 8, j = r3 % 8;
        int kt = step >> 1, ch = step & 1;
        int m = mf * 16 + l, c = ch * 32 + gg * 8 + j;
        wz2[t] = (m < 18) ? f2bf(w_off[(m * 64 + c) * 9 + kt]) : (short)0;
    }
    if (t < 9216) {
        int step = t / 512, r = t % 512;
        int l = r / 32, r3 = r % 32;
        int gg = r3 / 8, j = r3 % 8;
        int kt = step >> 1, ch = step & 1;
        int c = ch * 32 + gg * 8 + j;
        wx2[t] = (l < 9) ? f2bf(w_mod[(l * 64 + c) * 9 + kt]) : (short)0;
    }
}

// ---------------------------------------------------------------------------
// Prep 2: NCHW fp32 -> NHWC bf16 for x and z.
// ---------------------------------------------------------------------------
__global__ __launch_bounds__(256) void to_nhwc(
    const float* __restrict__ x, const float* __restrict__ z,
    unsigned short* __restrict__ xn, unsigned short* __restrict__ zn) {
    __shared__ float t[64 * 65];
    const int bid = blockIdx.x;
    const int xseg = bid & 1;
    const int y = (bid >> 1) & 127;
    const int b = bid >> 8;

#pragma unroll
    for (int arr = 0; arr < 2; ++arr) {
        const float* src = arr ? z : x;
        unsigned short* dst = arr ? zn : xn;
#pragma unroll
        for (int i = 0; i < 16; ++i) {
            int e = threadIdx.x + i * 256;
            int c = e >> 6, px = e & 63;
            t[px * 65 + c] =
                src[((size_t)(b * 64 + c) * H_ + y) * W_ + xseg * 64 + px];
        }
        __syncthreads();
#pragma unroll
        for (int i = 0; i < 2; ++i) {
            int j = threadIdx.x + i * 256;
            int px = j >> 3, q = j & 7;
            bf16x8 v;
#pragma unroll
            for (int jj = 0; jj < 8; ++jj)
                v[jj] = f2bf(t[px * 65 + q * 8 + jj]);
            *(bf16x8*)(dst +
                       ((size_t)((b * H_ + y) * W_ + xseg * 64 + px)) * 64 +
                       q * 8) = v;
        }
        __syncthreads();
    }
}

// bilinear tap parameters; offsets are int ELEMENT offsets into NHWC image
__device__ __forceinline__ void tap_params(
    int kt, int ho, int pxi, float dy, float dx, float m,
    float& w00, float& w01, float& w10, float& w11,
    int& a00, int& a01, int& a10, int& a11) {
    float py = dy + (float)(kt / 3 + ho - 1);
    float pxf = dx + (float)(kt % 3 + pxi - 1);
    float y0f = floorf(py), x0f = floorf(pxf);
    float wy1 = py - y0f, wy0 = 1.f - wy1;
    float wx1 = pxf - x0f, wx0w = 1.f - wx1;
    int y0 = (int)y0f, x0i = (int)x0f;
    int y1 = y0 + 1, x1 = x0i + 1;
    bool vy0 = (y0 >= 0) && (y0 < H_), vy1 = (y1 >= 0) && (y1 < H_);
    bool vx0 = (x0i >= 0) && (x0i < W_), vx1 = (x1 >= 0) && (x1 < W_);
    w00 = wy0 * wx0w * ((vy0 && vx0) ? m : 0.f);
    w01 = wy0 * wx1 * ((vy0 && vx1) ? m : 0.f);
    w10 = wy1 * wx0w * ((vy1 && vx0) ? m : 0.f);
    w11 = wy1 * wx1 * ((vy1 && vx1) ? m : 0.f);
    int y0c = min(max(y0, 0), H_ - 1), y1c = min(max(y1, 0), H_ - 1);
    int x0c = min(max(x0i, 0), W_ - 1), x1c = min(max(x1, 0), W_ - 1);
    a00 = (y0c * W_ + x0c) * 64;
    a01 = (y0c * W_ + x1c) * 64;
    a10 = (y1c * W_ + x0c) * 64;
    a11 = (y1c * W_ + x1c) * 64;
}

// ---------------------------------------------------------------------------
// FUSED conv + deform. One wave per 16 pixels. R10: ALL hot loads (corner
// gathers + weight frags) go global->LDS via global_load_lds into a PRIVATE
// per-wave 8KB buffer: zero dest VGPRs -> full-batch MLP at LOW register
// count -> MLP and TLP no longer in tension (R8/R9 saddle). Per step:
// issue loads -> vmcnt(0) -> ds_read own slot -> blend/MFMA -> lgkmcnt(0)
// (WAR fence). No __syncthreads anywhere (buffers wave-private).
// ---------------------------------------------------------------------------
__global__ __launch_bounds__(256, 3) void dcn_fused(
    const unsigned short* __restrict__ zn, const unsigned short* __restrict__ xn,
    const short* __restrict__ wb2, const short* __restrict__ wz2,
    const short* __restrict__ wx2,
    const float* __restrict__ b_off, const float* __restrict__ b_mod,
    float* __restrict__ out)
{
    __shared__ __align__(16) short sbuf[4][4096];  // 8KB per wave, private

    const int tid = threadIdx.x;
    const int lane = tid & 63;
    const int wv = tid >> 6;
    const int l15 = lane & 15;
    const int g = lane >> 4;

    // XCD swizzle: 2048 blocks = 8 XCDs x 256; one image per XCD L2.
    int bid = (int)blockIdx.x;
    bid = (bid & 7) * 256 + (bid >> 3);

    const int p0 = (bid * 4 + wv) * 16;
    const int b = p0 / HW_;
    const int pix0 = p0 % HW_;
    const int ho = pix0 / W_;
    const int wx0 = pix0 % W_;
    const int px = wx0 + l15;

    const unsigned short* znb = zn + (size_t)b * HW_ * 64;
    const unsigned short* xnb = xn + (size_t)b * HW_ * 64;
    const int g8 = g * 8;

    short* buf = &sbuf[wv][0];
    const int lofs = lane * 8;  // this lane's 16B slot (in shorts)

    // ---------------- Phase A: offset/mask convs ----------------
    f32x4 A0 = {0.f, 0.f, 0.f, 0.f}, A1 = A0, A2 = A0;
    const bf16x8 vzero = {0, 0, 0, 0, 0, 0, 0, 0};

#pragma unroll
    for (int kt = 0; kt < 9; ++kt) {
        const int iy = ho + kt / 3 - 1;
        const int ixl = px + kt % 3 - 1;
        const bool v = (iy >= 0) && (iy < H_) && (ixl >= 0) && (ixl < W_);
        const int iyc = min(max(iy, 0), H_ - 1);
        const int ixc = min(max(ixl, 0), W_ - 1);
        const int base = (iyc * W_ + ixc) * 64;
#pragma unroll
        for (int ch = 0; ch < 2; ++ch) {
            const int step = kt * 2 + ch;
            const int cb = ch * 32 + g8;
            gl16(znb + base + cb, buf + 0 * 512);
            gl16(xnb + base + cb, buf + 1 * 512);
            gl16(wz2 + (size_t)((step * 2 + 0) * 16 + l15) * 32 + g8,
                 buf + 2 * 512);
            gl16(wz2 + (size_t)((step * 2 + 1) * 16 + l15) * 32 + g8,
                 buf + 3 * 512);
            gl16(wx2 + (size_t)(step * 16 + l15) * 32 + g8, buf + 4 * 512);
            asm volatile("s_waitcnt vmcnt(0)" ::: "memory");
            __builtin_amdgcn_sched_barrier(0);

            bf16x8 bz = *(const bf16x8*)(buf + 0 * 512 + lofs);
            bf16x8 bx = *(const bf16x8*)(buf + 1 * 512 + lofs);
            bf16x8 az0 = *(const bf16x8*)(buf + 2 * 512 + lofs);
            bf16x8 az1 = *(const bf16x8*)(buf + 3 * 512 + lofs);
            bf16x8 ax = *(const bf16x8*)(buf + 4 * 512 + lofs);
            bz = v ? bz : vzero;
            bx = v ? bx : vzero;

            A0 = __builtin_amdgcn_mfma_f32_16x16x32_bf16(az0, bz, A0, 0, 0, 0);
            A1 = __builtin_amdgcn_mfma_f32_16x16x32_bf16(az1, bz, A1, 0, 0, 0);
            A2 = __builtin_amdgcn_mfma_f32_16x16x32_bf16(ax, bx, A2, 0, 0, 0);
            asm volatile("s_waitcnt lgkmcnt(0)" ::: "memory");  // buffer WAR
        }
    }

    // ---------------- Bridge: bias + sigmoid, then hoist all shfls ---------
#pragma unroll
    for (int r = 0; r < 4; ++r) A0[r] += b_off[g * 4 + r];
    if (g == 0) {
        A1[0] += b_off[16];
        A1[1] += b_off[17];
    }
    float mk[4];
#pragma unroll
    for (int r = 0; r < 4; ++r) {
        int jm = g * 4 + r;
        jm = (jm > 8) ? 8 : jm;
        mk[r] = 2.f / (1.f + expf(-(A2[r] + b_mod[jm])));
    }

    float dyA[9], dxA[9], mA[9];
#pragma unroll
    for (int kt = 0; kt < 9; ++kt) {
        if (kt < 8) {
            dyA[kt] = __shfl(A0[(2 * kt) & 3], ((2 * kt) >> 2) * 16 + l15, 64);
            dxA[kt] =
                __shfl(A0[(2 * kt + 1) & 3], ((2 * kt + 1) >> 2) * 16 + l15, 64);
        } else {
            dyA[kt] = __shfl(A1[0], l15, 64);
            dxA[kt] = __shfl(A1[1], l15, 64);
        }
        mA[kt] = __shfl(mk[kt & 3], (kt >> 2) * 16 + l15, 64);
    }

    // ---------------- Phase B: deformable conv ----------------
    f32x4 D0 = {0.f, 0.f, 0.f, 0.f}, D1 = D0, D2 = D0, D3 = D0;

#pragma unroll
    for (int kt = 0; kt < 9; ++kt) {
        float w00, w01, w10, w11;
        int a00, a01, a10, a11;
        tap_params(kt, ho, wx0 + l15, dyA[kt], dxA[kt], mA[kt], w00, w01, w10,
                   w11, a00, a01, a10, a11);
#pragma unroll
        for (int ch = 0; ch < 2; ++ch) {
            const int step = kt * 2 + ch;
            const int cb = ch * 32 + g8;
            gl16(xnb + a00 + cb, buf + 0 * 512);
            gl16(xnb + a01 + cb, buf + 1 * 512);
            gl16(xnb + a10 + cb, buf + 2 * 512);
            gl16(xnb + a11 + cb, buf + 3 * 512);
            gl16(wb2 + (size_t)((step * 4 + 0) * 16 + l15) * 32 + g8,
                 buf + 4 * 512);
            gl16(wb2 + (size_t)((step * 4 + 1) * 16 + l15) * 32 + g8,
                 buf + 5 * 512);
            gl16(wb2 + (size_t)((step * 4 + 2) * 16 + l15) * 32 + g8,
                 buf + 6 * 512);
            gl16(wb2 + (size_t)((step * 4 + 3) * 16 + l15) * 32 + g8,
                 buf + 7 * 512);
            asm volatile("s_waitcnt vmcnt(0)" ::: "memory");
            __builtin_amdgcn_sched_barrier(0);

            bf16x8 c0 = *(const bf16x8*)(buf + 0 * 512 + lofs);
            bf16x8 c1 = *(const bf16x8*)(buf + 1 * 512 + lofs);
            bf16x8 c2 = *(const bf16x8*)(buf + 2 * 512 + lofs);
            bf16x8 c3 = *(const bf16x8*)(buf + 3 * 512 + lofs);
            bf16x8 a0 = *(const bf16x8*)(buf + 4 * 512 + lofs);
            bf16x8 a1 = *(const bf16x8*)(buf + 5 * 512 + lofs);
            bf16x8 a2 = *(const bf16x8*)(buf + 6 * 512 + lofs);
            bf16x8 a3 = *(const bf16x8*)(buf + 7 * 512 + lofs);

            bf16x8 sv;
#pragma unroll
            for (int j = 0; j < 8; ++j) {
                float s = fmaf(bf2f(c0[j]), w00,
                          fmaf(bf2f(c1[j]), w01,
                          fmaf(bf2f(c2[j]), w10, bf2f(c3[j]) * w11)));
                sv[j] = f2bf(s);
            }
            D0 = __builtin_amdgcn_mfma_f32_16x16x32_bf16(a0, sv, D0, 0, 0, 0);
            D1 = __builtin_amdgcn_mfma_f32_16x16x32_bf16(a1, sv, D1, 0, 0, 0);
            D2 = __builtin_amdgcn_mfma_f32_16x16x32_bf16(a2, sv, D2, 0, 0, 0);
            D3 = __builtin_amdgcn_mfma_f32_16x16x32_bf16(a3, sv, D3, 0, 0, 0);
            asm volatile("s_waitcnt lgkmcnt(0)" ::: "memory");  // buffer WAR
        }
    }

    // epilogue: o = mf*16 + g*4 + r, pixel = pix0 + l15
#pragma unroll
    for (int mf = 0; mf < 4; ++mf) {
        f32x4 cc = (mf == 0) ? D0 : ((mf == 1) ? D1 : ((mf == 2) ? D2 : D3));
#pragma unroll
        for (int r = 0; r < 4; ++r) {
            const int o = mf * 16 + g * 4 + r;
            out[((size_t)b * O_ + o) * HW_ + pix0 + l15] = cc[r];
        }
    }
}

// ---------------------------------------------------------------------------
// Fallback (no workspace): fully fused fp32, slow but correct.
// ---------------------------------------------------------------------------
__global__ __launch_bounds__(256) void deform_fallback(
    const float* __restrict__ x, const float* __restrict__ z,
    const float* __restrict__ w_regp,
    const float* __restrict__ w_off, const float* __restrict__ b_off,
    const float* __restrict__ w_mod, const float* __restrict__ b_mod,
    float* __restrict__ out) {
    int p = blockIdx.x * blockDim.x + threadIdx.x;
    if (p >= B_ * HW_) return;
    int wo = p % W_;
    int ho = (p / W_) % H_;
    int b  = p / HW_;
    int pix = ho * W_ + wo;

    const float* xb = x + (size_t)b * C_ * HW_;

    float accO[18], accM[9];
#pragma unroll
    for (int j = 0; j < 18; ++j) accO[j] = b_off[j];
#pragma unroll
    for (int j = 0; j < 9; ++j) accM[j] = b_mod[j];
    const float* zb = z + (size_t)b * C_ * HW_;
#pragma unroll 1
    for (int c = 0; c < C_; ++c) {
        const float* zc = zb + c * HW_;
        const float* xc = xb + c * HW_;
#pragma unroll
        for (int ky = 0; ky < 3; ++ky) {
            int iy = ho + ky - 1;
            bool vy = (iy >= 0) && (iy < H_);
#pragma unroll
            for (int kx = 0; kx < 3; ++kx) {
                int ix = wo + kx - 1;
                bool v = vy && (ix >= 0) && (ix < W_);
                int k = ky * 3 + kx;
                float zv = v ? zc[iy * W_ + ix] : 0.f;
                float xv = v ? xc[iy * W_ + ix] : 0.f;
#pragma unroll
                for (int j = 0; j < 18; ++j)
                    accO[j] = fmaf(zv, w_off[j * 576 + c * 9 + k], accO[j]);
#pragma unroll
                for (int j = 0; j < 9; ++j)
                    accM[j] = fmaf(xv, w_mod[j * 576 + c * 9 + k], accM[j]);
            }
        }
    }
    float mv[9];
#pragma unroll
    for (int j = 0; j < 9; ++j) mv[j] = 2.f / (1.f + expf(-accM[j]));

    float acc[64];
#pragma unroll
    for (int o = 0; o < 64; ++o) acc[o] = 0.f;

#pragma unroll 1
    for (int k = 0; k < 9; ++k) {
        float dy = accO[2 * k], dx = accO[2 * k + 1], m = mv[k];
        float py = dy + (float)(k / 3 + ho - 1);
        float px = dx + (float)(k % 3 + wo - 1);
        float y0f = floorf(py), x0f = floorf(px);
        float wy1 = py - y0f, wy0 = 1.f - wy1;
        float wx1 = px - x0f, wx0 = 1.f - wx1;
        int y0 = (int)y0f, x0i = (int)x0f;
        int y1 = y0 + 1, x1 = x0i + 1;
        bool vy0 = (y0 >= 0) && (y0 < H_), vy1 = (y1 >= 0) && (y1 < H_);
        bool vx0 = (x0i >= 0) && (x0i < W_), vx1 = (x1 >= 0) && (x1 < W_);
        float w00 = wy0 * wx0 * ((vy0 && vx0) ? m : 0.f);
        float w01 = wy0 * wx1 * ((vy0 && vx1) ? m : 0.f);
        float w10 = wy1 * wx0 * ((vy1 && vx0) ? m : 0.f);
        float w11 = wy1 * wx1 * ((vy1 && vx1) ? m : 0.f);
        int y0c = min(max(y0, 0), H_ - 1), y1c = min(max(y1, 0), H_ - 1);
        int x0c = min(max(x0i, 0), W_ - 1), x1c = min(max(x1, 0), W_ - 1);
        int i00 = y0c * W_ + x0c, i01 = y0c * W_ + x1c;
        int i10 = y1c * W_ + x0c, i11 = y1c * W_ + x1c;
#pragma unroll 1
        for (int c = 0; c < C_; ++c) {
            const float* xc = xb + c * HW_;
            float val = xc[i00] * w00 + xc[i01] * w01 + xc[i10] * w10 +
                        xc[i11] * w11;
            const float* wr = w_regp + c * 9 + k;
#pragma unroll
            for (int o = 0; o < 64; ++o)
                acc[o] = fmaf(val, wr[o * 576], acc[o]);
        }
    }
    float* ob = out + (size_t)b * O_ * HW_ + pix;
#pragma unroll
    for (int o = 0; o < 64; ++o) ob[o * HW_] = acc[o];
}

// ---------------------------------------------------------------------------
extern "C" void kernel_launch(void* const* d_in, const int* in_sizes, int n_in,
                              void* d_out, int out_size, void* d_ws,
                              size_t ws_size, hipStream_t stream) {
    const float* x     = (const float*)d_in[0];
    const float* z     = (const float*)d_in[1];
    const float* w_off = (const float*)d_in[2];
    const float* b_off = (const float*)d_in[3];
    const float* w_mod = (const float*)d_in[4];
    const float* b_mod = (const float*)d_in[5];
    const float* w_reg = (const float*)d_in[6];
    float* out = (float*)d_out;

    // ws layout (bytes): wb2 73728 | wz2 36864 | wx2 18432  -> 129024
    //                    xn 16777216 | zn 16777216
    const size_t need = 129024 + 2 * 16777216ull;

    const int npix = B_ * HW_;   // 131072
    const int nblk = npix / 64;  // 2048 blocks (4 waves x 16 px)

    if (ws_size >= need) {
        short* wb2 = (short*)d_ws;
        short* wz2 = wb2 + 36864;
        short* wx2 = wz2 + 18432;
        unsigned short* xn = (unsigned short*)((char*)d_ws + 129024);
        unsigned short* zn = xn + 8388608;

        prep_weights<<<144, 256, 0, stream>>>(w_off, w_mod, w_reg, wb2, wz2,
                                              wx2);
        to_nhwc<<<2048, 256, 0, stream>>>(x, z, xn, zn);
        dcn_fused<<<nblk, 256, 0, stream>>>(zn, xn, wb2, wz2, wx2, b_off,
                                            b_mod, out);
    } else {
        deform_fallback<<<(npix + 255) / 256, 256, 0, stream>>>(
            x, z, w_reg, w_off, b_off, w_mod, b_mod, out);
    }
}